// Round 10
// baseline (223.961 us; speedup 1.0000x reference)
//
#include <hip/hip_runtime.h>
#include <math.h>

// QuantumNeuralNetwork: 12-qubit, 16-layer RY+CNOT-ring state-vector sim.
// Round 19: round-18 design, compile fix only (ACC16 token-pasting: P##0.x
// lexed 0.x as one pp-number -> paste error; now ACC1(P,i,V) parameterized).
// TWO STATES PER BLOCK with offset software pipeline.
// Diagnosis r14-r17: LDS data pipe is the floor (~82 us/CU: 64 b64/wave-layer
// x 6 cyc), wall 121-130 => pipe only ~68% fed. Gate-compute phases idle the
// DS pipe; inter-block staggering doesn't fill it (r17 null result).
// Fix: deterministic intra-wave overlap. Block = 256 thr, simulates states
// A (2b) and B (2b+1), phases offset by half a trip-cycle. Every slot:
//     [X trip-write ; Y gates ; barrier ; X trip-read]
// so trip writes drain under the other state's FMAs, reads hide under the
// next slot. 4 slots/layer = 4 barriers for TWO states (2/state, < r14's 3).
// Pipeline (P1=L1gates P2=trip1 P3=L2gates P4=trip2+perm):
//   prologue: B.P1(0) B.P2(0) B.P3(0)
//   loop l:  slot1 [B.W2(l)   A.P1(l)    bar B.R2(l)  ]
//            slot2 [A.W1(l)   B.P1(l+1)* bar A.R1(l)  ]
//            slot3 [B.W1(l+1)* A.P3(l)   bar B.R1(l+1)*]
//            slot4 [A.W2(l)   B.P3(l+1)* bar A.R2(l)  ]   (* skipped l=15)
// Hazard audit (all cross-thread W/R pairs barrier-separated):
//   A.W1(l) vs A.R2(l-1): bar_a(l). A.W2 vs A.R1: bar_c. A.R2 vs A.W1(l+1):
//   bar_a(l+1). B.W2(l) vs B.R1(l): bar_d(l-1). B.W1(l+1) vs B.R2(l): bar_b.
//   B.R1 vs B.W2: bar_d. Prologue R1->slot1 W2: per-thread-disjoint address
//   sets (W2 addrs == own R1 addrs, r14-proven) -> no bar needed.
// LDS 2x32KB = 64KB (2 blk/CU); VGPR target <=128 (64 state + ~30 misc);
// NO launch-bounds clamp (r16 spill lesson). Gates identical to r14: tan
// shears, per-wave trig table + readlane, all-DPP lane gates (tn = t^3*t2),
// global (prod C)^2 deferral. Numerics bit-identical per state.

#define DIM     4096
#define NLAYERS 16
#define BATCH   2048
#define NCLASS  5

typedef float v2f __attribute__((ext_vector_type(2)));

__host__ __device__ constexpr unsigned gperm(unsigned i) {
  for (int q = 11; q >= 0; --q) {
    const unsigned cbit = 1u << (11 - q);
    const unsigned tbit = 1u << (11 - ((q + 1) % 12));
    if (i & cbit) i ^= tbit;
  }
  return i;
}
__host__ __device__ constexpr unsigned Qmap(unsigned lo) {
  return ((lo ^ (lo >> 3)) & 1u) | ((((lo >> 1) ^ (lo >> 3)) & 1u) << 1) |
         (((lo >> 2) & 1u) << 2) | ((lo & 1u) << 3);
}
__host__ __device__ constexpr unsigned Fmap(unsigned x) {
  return (x & 0xF00u) | ((x & 0xFu) << 4) | (((x >> 4) & 0xFu) ^ Qmap(x & 0xFu));
}

#define W1C(i) ((int)Fmap((unsigned)(i)))
#define R2C(i) ((int)Fmap(gperm((unsigned)(i))))

// ---- gate building blocks (prefix P selects state A/B register set) ----
#define ROT(P, i, j) {                                        \
    const v2f ti = P##i, tj = P##j;                           \
    P##i = __builtin_elementwise_fma(nkv, tj, ti);            \
    P##j = __builtin_elementwise_fma(kv,  ti, tj); }

#define GM8(P) ROT(P,0,8) ROT(P,1,9) ROT(P,2,10) ROT(P,3,11) ROT(P,4,12) \
  ROT(P,5,13) ROT(P,6,14) ROT(P,7,15)
#define GM4(P) ROT(P,0,4) ROT(P,1,5) ROT(P,2,6) ROT(P,3,7) ROT(P,8,12) \
  ROT(P,9,13) ROT(P,10,14) ROT(P,11,15)
#define GM2(P) ROT(P,0,2) ROT(P,1,3) ROT(P,4,6) ROT(P,5,7) ROT(P,8,10) \
  ROT(P,9,11) ROT(P,12,14) ROT(P,13,15)
#define GM1(P) ROT(P,0,1) ROT(P,2,3) ROT(P,4,5) ROT(P,6,7) ROT(P,8,9) \
  ROT(P,10,11) ROT(P,12,13) ROT(P,14,15)

#define GETKL(g, LL) \
  const float kG = __int_as_float(__builtin_amdgcn_readlane( \
      __float_as_int(vkg[(g) & 3]), (LL) + (((g) >> 2) << 4)));

// fused DPP shear on 8 v2f (16 comps): p += sg * dpp_xor(p); s_nop 1 covers
// the VALU-write -> DPP-read hazard; 16 distinct dsts -> no intra-block hazard
#define DPP8(P, CTRL, iA,iB,iC,iD,iE,iF,iG,iH) { \
    float a0 = P##iA.x, a1 = P##iA.y, a2 = P##iB.x, a3 = P##iB.y, \
          a4 = P##iC.x, a5 = P##iC.y, a6 = P##iD.x, a7 = P##iD.y, \
          a8 = P##iE.x, a9 = P##iE.y, a10 = P##iF.x, a11 = P##iF.y, \
          a12 = P##iG.x, a13 = P##iG.y, a14 = P##iH.x, a15 = P##iH.y; \
    asm("s_nop 1\n\t" \
        "v_fmac_f32_dpp %0, %0, %16 " CTRL "\n\t" \
        "v_fmac_f32_dpp %1, %1, %16 " CTRL "\n\t" \
        "v_fmac_f32_dpp %2, %2, %16 " CTRL "\n\t" \
        "v_fmac_f32_dpp %3, %3, %16 " CTRL "\n\t" \
        "v_fmac_f32_dpp %4, %4, %16 " CTRL "\n\t" \
        "v_fmac_f32_dpp %5, %5, %16 " CTRL "\n\t" \
        "v_fmac_f32_dpp %6, %6, %16 " CTRL "\n\t" \
        "v_fmac_f32_dpp %7, %7, %16 " CTRL "\n\t" \
        "v_fmac_f32_dpp %8, %8, %16 " CTRL "\n\t" \
        "v_fmac_f32_dpp %9, %9, %16 " CTRL "\n\t" \
        "v_fmac_f32_dpp %10, %10, %16 " CTRL "\n\t" \
        "v_fmac_f32_dpp %11, %11, %16 " CTRL "\n\t" \
        "v_fmac_f32_dpp %12, %12, %16 " CTRL "\n\t" \
        "v_fmac_f32_dpp %13, %13, %16 " CTRL "\n\t" \
        "v_fmac_f32_dpp %14, %14, %16 " CTRL "\n\t" \
        "v_fmac_f32_dpp %15, %15, %16 " CTRL \
        : "+v"(a0), "+v"(a1), "+v"(a2), "+v"(a3), "+v"(a4), "+v"(a5), \
          "+v"(a6), "+v"(a7), "+v"(a8), "+v"(a9), "+v"(a10), "+v"(a11), \
          "+v"(a12), "+v"(a13), "+v"(a14), "+v"(a15) \
        : "v"(sg)); \
    P##iA.x = a0;  P##iA.y = a1;  P##iB.x = a2;  P##iB.y = a3; \
    P##iC.x = a4;  P##iC.y = a5;  P##iD.x = a6;  P##iD.y = a7; \
    P##iE.x = a8;  P##iE.y = a9;  P##iF.x = a10; P##iF.y = a11; \
    P##iG.x = a12; P##iG.y = a13; P##iH.x = a14; P##iH.y = a15; }

#define DPPGATE(P, CTRL) \
  DPP8(P, CTRL, 0,1,2,3,4,5,6,7) DPP8(P, CTRL, 8,9,10,11,12,13,14,15)

#define L1GATES(P, LL) \
  { GETKL(8,LL)  const v2f kv={kG,kG}, nkv={-kG,-kG}; GM8(P) } \
  { GETKL(9,LL)  const v2f kv={kG,kG}, nkv={-kG,-kG}; GM4(P) } \
  { GETKL(10,LL) const v2f kv={kG,kG}, nkv={-kG,-kG}; GM2(P) } \
  { GETKL(11,LL) const v2f kv={kG,kG}, nkv={-kG,-kG}; GM1(P) } \
  { GETKL(7,LL) const float sg = m7 ? kG : -kG; \
    DPPGATE(P, "quad_perm:[1,0,3,2] row_mask:0xf bank_mask:0xf") } \
  { GETKL(6,LL) const float sg = m6 ? kG : -kG; \
    DPPGATE(P, "quad_perm:[2,3,0,1] row_mask:0xf bank_mask:0xf") } \
  { GETKL(5,LL) const float sg = m5 ? kG : -kG; \
    DPPGATE(P, "row_half_mirror row_mask:0xf bank_mask:0xf") } \
  { GETKL(4,LL) const float sg = m4 ? kG : -kG; \
    DPPGATE(P, "row_ror:8 row_mask:0xf bank_mask:0xf") }

#define L2GATES(P, LL) \
  { GETKL(0,LL) const v2f kv={kG,kG}, nkv={-kG,-kG}; GM8(P) } \
  { GETKL(1,LL) const v2f kv={kG,kG}, nkv={-kG,-kG}; GM4(P) } \
  { GETKL(2,LL) const v2f kv={kG,kG}, nkv={-kG,-kG}; GM2(P) } \
  { GETKL(3,LL) const v2f kv={kG,kG}, nkv={-kG,-kG}; GM1(P) }

// ---- trips (B = LDS buffer pointer) ----
#define W1S(P,B,i) B[w1b ^ W1C(i)] = P##i;
#define TRIP1W(P,B) W1S(P,B,0) W1S(P,B,1) W1S(P,B,2) W1S(P,B,3) W1S(P,B,4) \
  W1S(P,B,5) W1S(P,B,6) W1S(P,B,7) W1S(P,B,8) W1S(P,B,9) W1S(P,B,10) \
  W1S(P,B,11) W1S(P,B,12) W1S(P,B,13) W1S(P,B,14) W1S(P,B,15)
#define R1S(P,B,i) P##i = B[r1b + ((i) << 8)];
#define TRIP1R(P,B) R1S(P,B,0) R1S(P,B,1) R1S(P,B,2) R1S(P,B,3) R1S(P,B,4) \
  R1S(P,B,5) R1S(P,B,6) R1S(P,B,7) R1S(P,B,8) R1S(P,B,9) R1S(P,B,10) \
  R1S(P,B,11) R1S(P,B,12) R1S(P,B,13) R1S(P,B,14) R1S(P,B,15)
#define W2S(P,B,i) B[r1b + ((i) << 8)] = P##i;
#define TRIP2W(P,B) W2S(P,B,0) W2S(P,B,1) W2S(P,B,2) W2S(P,B,3) W2S(P,B,4) \
  W2S(P,B,5) W2S(P,B,6) W2S(P,B,7) W2S(P,B,8) W2S(P,B,9) W2S(P,B,10) \
  W2S(P,B,11) W2S(P,B,12) W2S(P,B,13) W2S(P,B,14) W2S(P,B,15)
#define R2S(P,B,i) P##i = B[r2b ^ R2C(i)];
#define TRIP2R(P,B) R2S(P,B,0) R2S(P,B,1) R2S(P,B,2) R2S(P,B,3) R2S(P,B,4) \
  R2S(P,B,5) R2S(P,B,6) R2S(P,B,7) R2S(P,B,8) R2S(P,B,9) R2S(P,B,10) \
  R2S(P,B,11) R2S(P,B,12) R2S(P,B,13) R2S(P,B,14) R2S(P,B,15)

// ACC: element index via parameter so P##i pastes against an identifier
// token, never a pp-number like "0.x" (round-18 compile bug).
#define ACC1(P, i, V) \
  V = __builtin_fmaf(P##i.x, P##i.x, V); \
  V = __builtin_fmaf(P##i.y, P##i.y, V);
#define ACC16(P, V) \
  ACC1(P,0,V) ACC1(P,1,V) ACC1(P,2,V) ACC1(P,3,V) \
  ACC1(P,4,V) ACC1(P,5,V) ACC1(P,6,V) ACC1(P,7,V) \
  ACC1(P,8,V) ACC1(P,9,V) ACC1(P,10,V) ACC1(P,11,V) \
  ACC1(P,12,V) ACC1(P,13,V) ACC1(P,14,V) ACC1(P,15,V)

#define LOADSTATE(P, SRCR, SRCI) { \
    const float4* zr4 = (const float4*)(SRCR); \
    const float4* zi4 = (const float4*)(SRCI); \
    const float4 a0 = zr4[0], a1 = zr4[1], a2 = zr4[2], a3 = zr4[3]; \
    const float4 b0 = zi4[0], b1 = zi4[1], b2 = zi4[2], b3 = zi4[3]; \
    P##0  = (v2f){a0.x, b0.x}; P##1  = (v2f){a0.y, b0.y}; \
    P##2  = (v2f){a0.z, b0.z}; P##3  = (v2f){a0.w, b0.w}; \
    P##4  = (v2f){a1.x, b1.x}; P##5  = (v2f){a1.y, b1.y}; \
    P##6  = (v2f){a1.z, b1.z}; P##7  = (v2f){a1.w, b1.w}; \
    P##8  = (v2f){a2.x, b2.x}; P##9  = (v2f){a2.y, b2.y}; \
    P##10 = (v2f){a2.z, b2.z}; P##11 = (v2f){a2.w, b2.w}; \
    P##12 = (v2f){a3.x, b3.x}; P##13 = (v2f){a3.y, b3.y}; \
    P##14 = (v2f){a3.z, b3.z}; P##15 = (v2f){a3.w, b3.w}; }

__global__ __launch_bounds__(256)
void qnn_sim(const float* __restrict__ zr, const float* __restrict__ zi,
             const float* __restrict__ thetas, const int* __restrict__ y,
             float* __restrict__ out) {
  __shared__ v2f bufA[DIM];  // 32 KB: state A trip buffer
  __shared__ v2f bufB[DIM];  // 32 KB: state B trip buffer
  const int b = blockIdx.x;          // 0..1023
  const int sA = 2 * b, sB = 2 * b + 1;
  const int t = threadIdx.x;         // 0..255

  const int tn = t ^ (((t >> 2) & 1) * 3);
  const int w1b = ((t & 0xF0) << 4) | (tn & 0xF);   // F(tn<<4)
  const int r1b = (int)Fmap((unsigned)t);            // F(t)
  const int Gtn = ((tn << 4) ^ (tn << 3)) & 0xFFF;   // G(tn<<4)
  const int r2b = (int)Fmap((unsigned)Gtn);          // F(G(tn<<4))

  // DPP gate sign masks (same for both states)
  const bool m7 = ((t ^ (t >> 2)) & 1) != 0;
  const bool m6 = (((t >> 1) ^ (t >> 2)) & 1) != 0;
  const bool m5 = ((t >> 2) & 1) != 0;
  const bool m4 = ((t >> 3) & 1) != 0;

  v2f pA0,pA1,pA2,pA3,pA4,pA5,pA6,pA7,pA8,pA9,pA10,pA11,pA12,pA13,pA14,pA15;
  v2f pB0,pB1,pB2,pB3,pB4,pB5,pB6,pB7,pB8,pB9,pB10,pB11,pB12,pB13,pB14,pB15;

  LOADSTATE(pA, zr + (size_t)sA * DIM + (tn << 4), zi + (size_t)sA * DIM + (tn << 4))
  LOADSTATE(pB, zr + (size_t)sB * DIM + (tn << 4), zi + (size_t)sB * DIM + (tn << 4))

  // per-wave trig table: lanes 0..47 k-values, 48..63 C_l
  float vkg[4];
  {
    const int lane = t & 63;
    if (lane < 48) {
      const int lsrc = lane & 15;
      const int gb = (lane >> 4) << 2;
#pragma unroll
      for (int j = 0; j < 4; ++j) {
        const float a = 0.5f * thetas[lsrc * 12 + gb + j];
        vkg[j] = sinf(a) / cosf(a);
      }
    } else {
      const int lsrc = lane - 48;
      float c = 1.f;
      for (int g = 0; g < 12; ++g) c *= cosf(0.5f * thetas[lsrc * 12 + g]);
      vkg[0] = c; vkg[1] = 0.f; vkg[2] = 0.f; vkg[3] = 0.f;
    }
  }
  float pcl = 1.f;
#pragma unroll
  for (int l2 = 0; l2 < NLAYERS; ++l2)
    pcl *= __int_as_float(__builtin_amdgcn_readlane(
        __float_as_int(vkg[0]), 48 + l2));
  const float pc2 = pcl * pcl;

  // ---- B prologue: P1(0), P2(0), P3(0) ----
  L1GATES(pB, 0)
  TRIP1W(pB, bufB)
  __syncthreads();
  TRIP1R(pB, bufB)
  L2GATES(pB, 0)

#pragma unroll 1
  for (int l = 0; l < NLAYERS; ++l) {
    const bool more = (l < NLAYERS - 1);
    // slot1: B.W2(l) ; A.P1(l) ; bar_a ; B.R2(l)
    TRIP2W(pB, bufB)
    L1GATES(pA, l)
    __syncthreads();                    // bar_a
    TRIP2R(pB, bufB)
    // slot2: A.W1(l) ; B.P1(l+1) ; bar_b ; A.R1(l)
    TRIP1W(pA, bufA)
    if (more) { L1GATES(pB, l + 1) }
    __syncthreads();                    // bar_b
    TRIP1R(pA, bufA)
    // slot3: B.W1(l+1) ; A.P3(l) ; bar_c ; B.R1(l+1)
    if (more) { TRIP1W(pB, bufB) }
    L2GATES(pA, l)
    __syncthreads();                    // bar_c
    if (more) { TRIP1R(pB, bufB) }
    // slot4: A.W2(l) ; B.P3(l+1) ; bar_d ; A.R2(l)
    TRIP2W(pA, bufA)
    if (more) { L2GATES(pB, l + 1) }
    __syncthreads();                    // bar_d
    TRIP2R(pA, bufA)
  }

  // ---- Z expectations for both states ----
  float PA = 0.f, PB = 0.f;
  ACC16(pA, PA)
  ACC16(pB, PB)
  PA *= pc2;
  PB *= pc2;
  const float sg0 = ((t >> 7) & 1) ? -1.f : 1.f;
  const float sg1 = ((t >> 6) & 1) ? -1.f : 1.f;
  const float sg2 = ((t >> 5) & 1) ? -1.f : 1.f;
  const float sg3 = ((t >> 4) & 1) ? -1.f : 1.f;
  const float sg4 = ((t >> 3) & 1) ? -1.f : 1.f;
  float eA0 = sg0 * PA, eA1 = sg1 * PA, eA2 = sg2 * PA,
        eA3 = sg3 * PA, eA4 = sg4 * PA;
  float eB0 = sg0 * PB, eB1 = sg1 * PB, eB2 = sg2 * PB,
        eB3 = sg3 * PB, eB4 = sg4 * PB;
#pragma unroll
  for (int off = 32; off >= 1; off >>= 1) {
    eA0 += __shfl_xor(eA0, off); eA1 += __shfl_xor(eA1, off);
    eA2 += __shfl_xor(eA2, off); eA3 += __shfl_xor(eA3, off);
    eA4 += __shfl_xor(eA4, off);
    eB0 += __shfl_xor(eB0, off); eB1 += __shfl_xor(eB1, off);
    eB2 += __shfl_xor(eB2, off); eB3 += __shfl_xor(eB3, off);
    eB4 += __shfl_xor(eB4, off);
  }
  float* bf = (float*)bufA;
  __syncthreads();  // all A.R2(15)/B reads done before buf reuse
  if ((t & 63) == 0) {
    const int w8 = (t >> 6) * 8;
    bf[w8 + 0] = eA0; bf[w8 + 1] = eA1; bf[w8 + 2] = eA2;
    bf[w8 + 3] = eA3; bf[w8 + 4] = eA4;
    bf[32 + w8 + 0] = eB0; bf[32 + w8 + 1] = eB1; bf[32 + w8 + 2] = eB2;
    bf[32 + w8 + 3] = eB3; bf[32 + w8 + 4] = eB4;
  }
  __syncthreads();
  if (t == 0) {
    const float o0 = bf[0] + bf[8]  + bf[16] + bf[24];
    const float o1 = bf[1] + bf[9]  + bf[17] + bf[25];
    const float o2 = bf[2] + bf[10] + bf[18] + bf[26];
    const float o3 = bf[3] + bf[11] + bf[19] + bf[27];
    const float o4 = bf[4] + bf[12] + bf[20] + bf[28];
    float* op = out + 1 + (size_t)sA * NCLASS;
    op[0] = o0; op[1] = o1; op[2] = o2; op[3] = o3; op[4] = o4;
    const float m = fmaxf(fmaxf(fmaxf(o0, o1), fmaxf(o2, o3)), o4);
    const float sum = expf(o0 - m) + expf(o1 - m) + expf(o2 - m) +
                      expf(o3 - m) + expf(o4 - m);
    const int yb = y[sA];
    const float oy = (yb == 0) ? o0 : (yb == 1) ? o1 : (yb == 2) ? o2
                   : (yb == 3) ? o3 : o4;
    const float nll = (m + logf(sum)) - oy;
    atomicAdd(out, nll * (1.0f / BATCH));
  }
  if (t == 64) {
    const float o0 = bf[32+0] + bf[32+8]  + bf[32+16] + bf[32+24];
    const float o1 = bf[32+1] + bf[32+9]  + bf[32+17] + bf[32+25];
    const float o2 = bf[32+2] + bf[32+10] + bf[32+18] + bf[32+26];
    const float o3 = bf[32+3] + bf[32+11] + bf[32+19] + bf[32+27];
    const float o4 = bf[32+4] + bf[32+12] + bf[32+20] + bf[32+28];
    float* op = out + 1 + (size_t)sB * NCLASS;
    op[0] = o0; op[1] = o1; op[2] = o2; op[3] = o3; op[4] = o4;
    const float m = fmaxf(fmaxf(fmaxf(o0, o1), fmaxf(o2, o3)), o4);
    const float sum = expf(o0 - m) + expf(o1 - m) + expf(o2 - m) +
                      expf(o3 - m) + expf(o4 - m);
    const int yb = y[sB];
    const float oy = (yb == 0) ? o0 : (yb == 1) ? o1 : (yb == 2) ? o2
                   : (yb == 3) ? o3 : o4;
    const float nll = (m + logf(sum)) - oy;
    atomicAdd(out, nll * (1.0f / BATCH));
  }
}

extern "C" void kernel_launch(void* const* d_in, const int* in_sizes, int n_in,
                              void* d_out, int out_size, void* d_ws, size_t ws_size,
                              hipStream_t stream) {
  const float* zr = (const float*)d_in[0];
  const float* zi = (const float*)d_in[1];
  const float* th = (const float*)d_in[2];
  const int*   y  = (const int*)d_in[3];
  float* out = (float*)d_out;
  hipMemsetAsync(out, 0, sizeof(float), stream);  // zero loss accumulator
  qnn_sim<<<BATCH / 2, 256, 0, stream>>>(zr, zi, th, y, out);
}

// Round 11
// 192.334 us; speedup vs baseline: 1.1644x; 1.1644x over previous
//
#include <hip/hip_runtime.h>
#include <math.h>

// QuantumNeuralNetwork: 12-qubit, 16-layer RY+CNOT-ring state-vector sim.
// Round 20: r14 structure (the 121us plateau: 256 thr/state, 16 amps/lane,
// tan shears, per-wave trig table + readlane, all-DPP lane gates via
// tn = t^3*t2, 32KB buffer, 3 barriers/layer) + WRITE-INTERLEAVED final
// gates to hide the trip-write drain that __syncthreads forces (lgkmcnt(0)
// before s_barrier - the r18/r19 lesson):
//   - gates within a layer commute -> reorder so each half-layer ENDS with
//     the mask-1 pair gate (q11 for L1, q3 for L2). Its 8 ROTs each finalize
//     two amps independently; the amp's ds_write issues right after its ROT.
//     16 writes spread over ~32 pk_fmas instead of a post-gate burst.
//   - L1 order: DPP q7,q6,q5,q4 first (consumes R2 data in natural order),
//     then reg q8,q9,q10, bar0, then q11+W1 interleaved.
//   - R1 reads ordered (0,8),(1,9),... matching first L2 gate GM8 pairs.
// Address sets and barrier placement unchanged -> r14 hazard proofs hold:
//   bar0 (pre-W1, drain-free: R2 reads already consumed by DPP gates),
//   bar1 (W1->R1 transpose), NO bar before W2 (thread-own columns), bar2
//   (W2->R2 transpose). Structural minimality: 2 trips/layer (t6,t7 are
//   wave-select bits, not lane-gateable; swizzle alternatives move the same
//   bytes), full-block barriers (R1/R2 span all 16 wave-slots).
// Failed-structure ledger: 1-wave/0-bar = 267us; 16KB/7-bar = 130; 2-state
// pipeline/64KB = 149; r14 = 121. This round targets the write-drain stall.

#define DIM     4096
#define NLAYERS 16
#define BATCH   2048
#define NCLASS  5

typedef float v2f __attribute__((ext_vector_type(2)));

__host__ __device__ constexpr unsigned gperm(unsigned i) {
  for (int q = 11; q >= 0; --q) {
    const unsigned cbit = 1u << (11 - q);
    const unsigned tbit = 1u << (11 - ((q + 1) % 12));
    if (i & cbit) i ^= tbit;
  }
  return i;
}
// Q and F: the slot map (bank-proven rounds 6-14)
__host__ __device__ constexpr unsigned Qmap(unsigned lo) {
  return ((lo ^ (lo >> 3)) & 1u) | ((((lo >> 1) ^ (lo >> 3)) & 1u) << 1) |
         (((lo >> 2) & 1u) << 2) | ((lo & 1u) << 3);
}
__host__ __device__ constexpr unsigned Fmap(unsigned x) {
  return (x & 0xF00u) | ((x & 0xFu) << 4) | (((x >> 4) & 0xFu) ^ Qmap(x & 0xFu));
}

#define FOR16(M) M(0) M(1) M(2) M(3) M(4) M(5) M(6) M(7) M(8) M(9) M(10) \
  M(11) M(12) M(13) M(14) M(15)

// packed shear pair-rotation (kv, nkv in scope):
//   pi' = pi - k*pj ; pj' = pj + k*pi   (scalar c deferred globally)
#define ROT(i, j) {                                          \
    const v2f ti = p##i, tj = p##j;                          \
    p##i = __builtin_elementwise_fma(nkv, tj, ti);           \
    p##j = __builtin_elementwise_fma(kv,  ti, tj); }

#define GM8 ROT(0,8) ROT(1,9) ROT(2,10) ROT(3,11) ROT(4,12) ROT(5,13) \
  ROT(6,14) ROT(7,15)
#define GM4 ROT(0,4) ROT(1,5) ROT(2,6) ROT(3,7) ROT(8,12) ROT(9,13) \
  ROT(10,14) ROT(11,15)
#define GM2 ROT(0,2) ROT(1,3) ROT(4,6) ROT(5,7) ROT(8,10) ROT(9,11) \
  ROT(12,14) ROT(13,15)

// mask-1 pair gate fused with trip writes: finalize amps i,j then store them
#define ROTW1(i, j) ROT(i, j) buf2[w1a##i] = p##i; buf2[w1a##j] = p##j;
#define GM1W1 ROTW1(0,1) ROTW1(2,3) ROTW1(4,5) ROTW1(6,7) ROTW1(8,9) \
  ROTW1(10,11) ROTW1(12,13) ROTW1(14,15)
#define ROTW2(i, j) ROT(i, j) \
  buf2[r1b + ((i) << 8)] = p##i; buf2[r1b + ((j) << 8)] = p##j;
#define GM1W2 ROTW2(0,1) ROTW2(2,3) ROTW2(4,5) ROTW2(6,7) ROTW2(8,9) \
  ROTW2(10,11) ROTW2(12,13) ROTW2(14,15)

// broadcast k for (layer l, gate g) from the per-wave trig table:
// reg = g&3 (literal), lane = l + 16*(g>>2) (uniform SGPR)
#define GETK(g) \
  const float kG = __int_as_float(__builtin_amdgcn_readlane( \
      __float_as_int(vkg[(g) & 3]), l + (((g) >> 2) << 4)));

// fused DPP shear on 8 v2f (16 comps): p += sg * dpp_xor(p); s_nop 1 covers
// the VALU-write -> DPP-read hazard; 16 distinct dsts -> no intra-block hazard
#define DPP8(CTRL, iA,iB,iC,iD,iE,iF,iG,iH) { \
    float a0 = p##iA.x, a1 = p##iA.y, a2 = p##iB.x, a3 = p##iB.y, \
          a4 = p##iC.x, a5 = p##iC.y, a6 = p##iD.x, a7 = p##iD.y, \
          a8 = p##iE.x, a9 = p##iE.y, a10 = p##iF.x, a11 = p##iF.y, \
          a12 = p##iG.x, a13 = p##iG.y, a14 = p##iH.x, a15 = p##iH.y; \
    asm("s_nop 1\n\t" \
        "v_fmac_f32_dpp %0, %0, %16 " CTRL "\n\t" \
        "v_fmac_f32_dpp %1, %1, %16 " CTRL "\n\t" \
        "v_fmac_f32_dpp %2, %2, %16 " CTRL "\n\t" \
        "v_fmac_f32_dpp %3, %3, %16 " CTRL "\n\t" \
        "v_fmac_f32_dpp %4, %4, %16 " CTRL "\n\t" \
        "v_fmac_f32_dpp %5, %5, %16 " CTRL "\n\t" \
        "v_fmac_f32_dpp %6, %6, %16 " CTRL "\n\t" \
        "v_fmac_f32_dpp %7, %7, %16 " CTRL "\n\t" \
        "v_fmac_f32_dpp %8, %8, %16 " CTRL "\n\t" \
        "v_fmac_f32_dpp %9, %9, %16 " CTRL "\n\t" \
        "v_fmac_f32_dpp %10, %10, %16 " CTRL "\n\t" \
        "v_fmac_f32_dpp %11, %11, %16 " CTRL "\n\t" \
        "v_fmac_f32_dpp %12, %12, %16 " CTRL "\n\t" \
        "v_fmac_f32_dpp %13, %13, %16 " CTRL "\n\t" \
        "v_fmac_f32_dpp %14, %14, %16 " CTRL "\n\t" \
        "v_fmac_f32_dpp %15, %15, %16 " CTRL \
        : "+v"(a0), "+v"(a1), "+v"(a2), "+v"(a3), "+v"(a4), "+v"(a5), \
          "+v"(a6), "+v"(a7), "+v"(a8), "+v"(a9), "+v"(a10), "+v"(a11), \
          "+v"(a12), "+v"(a13), "+v"(a14), "+v"(a15) \
        : "v"(sg)); \
    p##iA.x = a0;  p##iA.y = a1;  p##iB.x = a2;  p##iB.y = a3; \
    p##iC.x = a4;  p##iC.y = a5;  p##iD.x = a6;  p##iD.y = a7; \
    p##iE.x = a8;  p##iE.y = a9;  p##iF.x = a10; p##iF.y = a11; \
    p##iG.x = a12; p##iG.y = a13; p##iH.x = a14; p##iH.y = a15; }

#define DPPGATE(CTRL) \
  DPP8(CTRL, 0,1,2,3,4,5,6,7) DPP8(CTRL, 8,9,10,11,12,13,14,15)

__global__ __launch_bounds__(256)
void qnn_sim(const float* __restrict__ zr, const float* __restrict__ zi,
             const float* __restrict__ thetas, const int* __restrict__ y,
             float* __restrict__ out) {
  __shared__ v2f buf2[DIM];  // 32 KB: (re,im) per amp, slot = F(amp)
  const int b = blockIdx.x;
  const int t = threadIdx.x;  // 0..255

  // lane-coordinate change: tn = t ^ 3*t2 (flips t1,t0 when t2 set)
  const int tn = t ^ (((t >> 2) & 1) * 3);

  // layer-invariant bases under F (L1 holder map uses tn; L2 uses t)
  const int w1b = ((t & 0xF0) << 4) | (tn & 0xF);                 // F(tn<<4)
  const int r1b = (int)Fmap((unsigned)t);                         // F(t)
  const int Gtn = ((tn << 4) ^ (tn << 3)) & 0xFFF;                // G(tn<<4)
  const int r2b = (int)Fmap((unsigned)Gtn);                       // F(G(tn<<4))

  // hoisted per-amp addresses (layer-invariant): W1 and R2
#define MKADDR(i) \
  const int w1a##i = w1b ^ (int)Fmap((unsigned)i); \
  const int r2a##i = r2b ^ (int)Fmap(gperm((unsigned)i));
  FOR16(MKADDR)
#undef MKADDR

  // DPP gate sign masks under the lane map
  const bool m7 = ((t ^ (t >> 2)) & 1) != 0;         // amp bit4 = t0^t2
  const bool m6 = (((t >> 1) ^ (t >> 2)) & 1) != 0;  // amp bit5 = t1^t2
  const bool m5 = ((t >> 2) & 1) != 0;               // amp bit6 = t2
  const bool m4 = ((t >> 3) & 1) != 0;               // amp bit7 = t3

  v2f p0,p1,p2,p3,p4,p5,p6,p7,p8,p9,p10,p11,p12,p13,p14,p15;
  {
    const float4* zr4 = (const float4*)(zr + (size_t)b * DIM + (tn << 4));
    const float4* zi4 = (const float4*)(zi + (size_t)b * DIM + (tn << 4));
    const float4 a0 = zr4[0], a1 = zr4[1], a2 = zr4[2], a3 = zr4[3];
    const float4 b0 = zi4[0], b1 = zi4[1], b2 = zi4[2], b3 = zi4[3];
    p0  = (v2f){a0.x, b0.x}; p1  = (v2f){a0.y, b0.y};
    p2  = (v2f){a0.z, b0.z}; p3  = (v2f){a0.w, b0.w};
    p4  = (v2f){a1.x, b1.x}; p5  = (v2f){a1.y, b1.y};
    p6  = (v2f){a1.z, b1.z}; p7  = (v2f){a1.w, b1.w};
    p8  = (v2f){a2.x, b2.x}; p9  = (v2f){a2.y, b2.y};
    p10 = (v2f){a2.z, b2.z}; p11 = (v2f){a2.w, b2.w};
    p12 = (v2f){a3.x, b3.x}; p13 = (v2f){a3.y, b3.y};
    p14 = (v2f){a3.z, b3.z}; p15 = (v2f){a3.w, b3.w};
  }

  // ---- per-wave trig table (once), 4 VGPRs:
  // lanes 0..47:  vkg[j] = tan(theta[lane&15][4*(lane>>4)+j] / 2)
  // lanes 48..63: vkg[0] = C_l = prod_{g=0..11} cos(th/2)   (layer = lane-48)
  float vkg[4];
  {
    const int lane = t & 63;
    if (lane < 48) {
      const int lsrc = lane & 15;          // source layer
      const int gb = (lane >> 4) << 2;     // gate group base: 0, 4, 8
#pragma unroll
      for (int j = 0; j < 4; ++j) {
        const float a = 0.5f * thetas[lsrc * 12 + gb + j];
        vkg[j] = sinf(a) / cosf(a);
      }
    } else {
      const int lsrc = lane - 48;
      float c = 1.f;
      for (int g = 0; g < 12; ++g) c *= cosf(0.5f * thetas[lsrc * 12 + g]);
      vkg[0] = c; vkg[1] = 0.f; vkg[2] = 0.f; vkg[3] = 0.f;
    }
  }
  // global deferred scale: (prod_l C_l)^2, applied to P at the end
  float pcl = 1.f;
#pragma unroll
  for (int l2 = 0; l2 < NLAYERS; ++l2)
    pcl *= __int_as_float(__builtin_amdgcn_readlane(
        __float_as_int(vkg[0]), 48 + l2));
  const float pc2 = pcl * pcl;

#pragma unroll 1
  for (int l = 0; l < NLAYERS; ++l) {
    // ---- L1 DPP gates FIRST (consume R2 data in natural 0..15 order) ----
    { GETK(7) const float sg = m7 ? kG : -kG;
      DPPGATE("quad_perm:[1,0,3,2] row_mask:0xf bank_mask:0xf") }
    { GETK(6) const float sg = m6 ? kG : -kG;
      DPPGATE("quad_perm:[2,3,0,1] row_mask:0xf bank_mask:0xf") }
    { GETK(5) const float sg = m5 ? kG : -kG;
      DPPGATE("row_half_mirror row_mask:0xf bank_mask:0xf") }
    { GETK(4) const float sg = m4 ? kG : -kG;
      DPPGATE("row_ror:8 row_mask:0xf bank_mask:0xf") }

    // ---- L1 reg gates q8,q9,q10 ----
    { GETK(8)  const v2f kv = {kG,kG}, nkv = {-kG,-kG}; GM8 }
    { GETK(9)  const v2f kv = {kG,kG}, nkv = {-kG,-kG}; GM4 }
    { GETK(10) const v2f kv = {kG,kG}, nkv = {-kG,-kG}; GM2 }

    __syncthreads();  // bar0: prev R2 reads done (drain-free: consumed above)

    // ---- q11 (mask-1 pairs) fused with W1: write each amp as finalized ----
    { GETK(11) const v2f kv = {kG,kG}, nkv = {-kG,-kG}; GM1W1 }

    __syncthreads();  // bar1: W1 drained (writes issued early, mostly done)

    // ---- R1: pair order (i, i+8) matching first L2 gate GM8 ----
    p0 = buf2[r1b];          p8  = buf2[r1b + 2048];
    p1 = buf2[r1b + 256];    p9  = buf2[r1b + 2304];
    p2 = buf2[r1b + 512];    p10 = buf2[r1b + 2560];
    p3 = buf2[r1b + 768];    p11 = buf2[r1b + 2816];
    p4 = buf2[r1b + 1024];   p12 = buf2[r1b + 3072];
    p5 = buf2[r1b + 1280];   p13 = buf2[r1b + 3328];
    p6 = buf2[r1b + 1536];   p14 = buf2[r1b + 3584];
    p7 = buf2[r1b + 1792];   p15 = buf2[r1b + 3840];

    // ---- L2 reg gates q0,q1,q2 ----
    { GETK(0) const v2f kv = {kG,kG}, nkv = {-kG,-kG}; GM8 }
    { GETK(1) const v2f kv = {kG,kG}, nkv = {-kG,-kG}; GM4 }
    { GETK(2) const v2f kv = {kG,kG}, nkv = {-kG,-kG}; GM2 }

    // ---- q3 (mask-1 pairs) fused with W2 (thread-own columns: no barrier
    // needed before these writes - same address sets as own R1, r14-proven) --
    { GETK(3) const v2f kv = {kG,kG}, nkv = {-kG,-kG}; GM1W2 }

    __syncthreads();  // bar2: W2 drained
#define R2P(i) p##i = buf2[r2a##i];
    FOR16(R2P)
#undef R2P
  }

  // ---- Z expectations: wire w sign = amp bit (11-w) ----
  float P = 0.f;
#define ACC(i) P = __builtin_fmaf(p##i.x, p##i.x, P); \
               P = __builtin_fmaf(p##i.y, p##i.y, P);
  FOR16(ACC)
#undef ACC
  P *= pc2;  // global deferred (prod C)^2
  float e0 = ((t >> 7) & 1) ? -P : P;
  float e1 = ((t >> 6) & 1) ? -P : P;
  float e2 = ((t >> 5) & 1) ? -P : P;
  float e3 = ((t >> 4) & 1) ? -P : P;
  float e4 = ((t >> 3) & 1) ? -P : P;
#pragma unroll
  for (int off = 32; off >= 1; off >>= 1) {
    e0 += __shfl_xor(e0, off);
    e1 += __shfl_xor(e1, off);
    e2 += __shfl_xor(e2, off);
    e3 += __shfl_xor(e3, off);
    e4 += __shfl_xor(e4, off);
  }
  float* bf = (float*)buf2;
  __syncthreads();  // last R2 reads done before buf reuse
  if ((t & 63) == 0) {
    const int w8 = (t >> 6) * 8;
    bf[w8 + 0] = e0; bf[w8 + 1] = e1; bf[w8 + 2] = e2;
    bf[w8 + 3] = e3; bf[w8 + 4] = e4;
  }
  __syncthreads();
  if (t == 0) {
    const float o0 = bf[0] + bf[8]  + bf[16] + bf[24];
    const float o1 = bf[1] + bf[9]  + bf[17] + bf[25];
    const float o2 = bf[2] + bf[10] + bf[18] + bf[26];
    const float o3 = bf[3] + bf[11] + bf[19] + bf[27];
    const float o4 = bf[4] + bf[12] + bf[20] + bf[28];
    float* op = out + 1 + (size_t)b * NCLASS;
    op[0] = o0; op[1] = o1; op[2] = o2; op[3] = o3; op[4] = o4;
    // fused NLL: loss contribution = (logsumexp(o) - o[y]) / BATCH
    const float m = fmaxf(fmaxf(fmaxf(o0, o1), fmaxf(o2, o3)), o4);
    const float sum = expf(o0 - m) + expf(o1 - m) + expf(o2 - m) +
                      expf(o3 - m) + expf(o4 - m);
    const int yb = y[b];
    const float oy = (yb == 0) ? o0 : (yb == 1) ? o1 : (yb == 2) ? o2
                   : (yb == 3) ? o3 : o4;
    const float nll = (m + logf(sum)) - oy;
    atomicAdd(out, nll * (1.0f / BATCH));
  }
}

extern "C" void kernel_launch(void* const* d_in, const int* in_sizes, int n_in,
                              void* d_out, int out_size, void* d_ws, size_t ws_size,
                              hipStream_t stream) {
  const float* zr = (const float*)d_in[0];
  const float* zi = (const float*)d_in[1];
  const float* th = (const float*)d_in[2];
  const int*   y  = (const int*)d_in[3];
  float* out = (float*)d_out;
  hipMemsetAsync(out, 0, sizeof(float), stream);  // zero loss accumulator
  qnn_sim<<<BATCH, 256, 0, stream>>>(zr, zi, th, y, out);
}